// Round 12
// baseline (362.018 us; speedup 1.0000x reference)
//
#include <hip/hip_runtime.h>

typedef unsigned int uint32;
typedef unsigned long long uint64;
typedef unsigned short ushortT;
typedef __attribute__((ext_vector_type(8))) short short8;
typedef __attribute__((ext_vector_type(4))) short short4v;
typedef __attribute__((ext_vector_type(4))) float floatx4;

#define DEV static __device__ __forceinline__

#define NN 2048
#define CC 64
#define KK 20

DEV float bf2f(ushortT h) {
  union { uint32 u; float f; } c; c.u = ((uint32)h) << 16; return c.f;
}
DEV ushortT f2bf(float f) {
  union { float f; uint32 u; } c; c.f = f;
  uint32 r = c.u + 0x7FFFu + ((c.u >> 16) & 1u);   // RNE
  return (ushortT)(r >> 16);
}
DEV void split2(float v, ushortT& h, ushortT& l) {
  h = f2bf(v);
  l = f2bf(v - bf2f(h));
}
DEV uint32 fmap(float f) {            // monotone f32 -> u32
  uint32 u = __float_as_uint(f);
  return (u & 0x80000000u) ? ~u : (u | 0x80000000u);
}
DEV float funmap(uint32 m) {
  uint32 u = (m & 0x80000000u) ? (m ^ 0x80000000u) : ~m;
  return __uint_as_float(u);
}
DEV short8 ld8(const ushortT* p) {    // 8B-aligned 16B load as two b64
  short4v a = *(const short4v*)p;
  short4v b = *(const short4v*)(p + 4);
  short8 r;
  r[0] = a.x; r[1] = a.y; r[2] = a.z; r[3] = a.w;
  r[4] = b.x; r[5] = b.y; r[6] = b.z; r[7] = b.w;
  return r;
}

// ---------------------------------------------------------------- K0: sq norms + bf16 image of x
__global__ void k_sq(const float* __restrict__ x, float* __restrict__ sq,
                     ushortT* __restrict__ xbf) {
  int p = blockIdx.x * 256 + threadIdx.x;
  const float4* row = (const float4*)(x + (size_t)p * CC);
  ushortT* orow = xbf + (size_t)p * CC;
  float s = 0.f;
#pragma unroll
  for (int q = 0; q < 16; ++q) {
    float4 v = row[q];
    s += v.x * v.x + v.y * v.y + v.z * v.z + v.w * v.w;
    short4v h;
    h.x = (short)f2bf(v.x); h.y = (short)f2bf(v.y);
    h.z = (short)f2bf(v.z); h.w = (short)f2bf(v.w);
    *(short4v*)(orow + q * 4) = h;
  }
  sq[p] = s;
}

// ---------------------------------------------------------------- K0b: one-time weight transpose+bf16
__global__ void k_wconv(const float* __restrict__ w1, const float* __restrict__ w2,
                        const float* __restrict__ w3, ushortT* __restrict__ wbf) {
  int t = threadIdx.x;
  for (int e = t; e < 4096; e += 256) {
    int n = e >> 6, k = e & 63;
    wbf[e]         = f2bf(w1[k * 64 + n]);
    wbf[4096 + e]  = f2bf(w1[(64 + k) * 64 + n]);
    wbf[8192 + e]  = f2bf(w2[k * 64 + n]);
    wbf[12288 + e] = f2bf(w3[k * 64 + n]);
  }
}

// ---------------------------------------------------------------- K1: KNN stage 1
// 64-wide j-tiles -> LDS 18.3KB -> 8 blocks/CU (32 waves/CU; was 4 blocks/36KB
// at 37% occupancy, latency-bound). sCand capacity == tile width (64): tile-0
// dense fills exactly 64, filtered tiles accept <=64 -> overflow IMPOSSIBLE by
// construction. Same MFMA count / tau-filter / owner-scan semantics; 32 tiles
// x 2 barriers hide behind the doubled wave count. launch_bounds(256,8)
// forces VGPR<=64 (est. ~56 live).
__launch_bounds__(256, 8)
__global__ void k_knn(const ushortT* __restrict__ xbf, const float* __restrict__ sq,
                      ushortT* __restrict__ cand) {
  const int b  = blockIdx.y;
  const int i0 = blockIdx.x * 32;
  const int t  = threadIdx.x;
  const int l  = t & 63, wv = t >> 6;
  const int la = l & 15, quad = l >> 4;
  const int pp = t >> 2, ss = t & 3;     // owners: t<128 -> rows 0..31

  __shared__ __align__(16) char sm[18304];
  ushortT (*sXj)[72]   = (ushortT(*)[72])(sm);           // 9216 B
  uint32  (*sCand)[66] = (uint32(*)[66])(sm + 9216);     // 8448 B -> 17664
  uint32*  sTau        = (uint32*)(sm + 17664);          // 128 B -> 17792
  uint32*  sCnt        = (uint32*)(sm + 17792);          // 128 B -> 17920
  float*   sSqi        = (float*)(sm + 17920);           // 128 B -> 18048
  float*   sSqj        = (float*)(sm + 18048);           // 256 B -> 18304

  const ushortT* xbb = xbf + ((size_t)b * NN) * CC;

  const int mw = wv & 1;             // which 16-row m-tile of the 32
  const int ng = wv >> 1;            // n-group: j-rows ng*32 .. ng*32+31

  short8 afrag[2];
  {
    const ushortT* rowp = xbb + (size_t)(i0 + mw * 16 + la) * CC;
#pragma unroll
    for (int ks = 0; ks < 2; ++ks)
      afrag[ks] = *(const short8*)(rowp + ks * 32 + quad * 8);
  }
  if (t < 32) sSqi[t] = sq[b * NN + i0 + t];

  // stage tile 0: 64 rows, 4 threads/row, 16 shorts (2x uint4) each
  {
    int r = t >> 2, co = (t & 3) * 16;
    const ushortT* src = xbb + (size_t)r * CC + co;
    *(uint4*)&sXj[r][co]     = *(const uint4*)(src);
    *(uint4*)&sXj[r][co + 8] = *(const uint4*)(src + 8);
  }
  if (t < 64) sSqj[t] = sq[b * NN + t];

  uint32 lst[KK];
#pragma unroll
  for (int s = 0; s < KK; ++s) lst[s] = 0xFFFFFFFFu;

  __syncthreads();

  float sqa[4];
  {
    float4 v = *(const float4*)&sSqi[mw * 16 + quad * 4];
    sqa[0] = v.x; sqa[1] = v.y; sqa[2] = v.z; sqa[3] = v.w;
  }

  for (int jt = 0; jt < 32; ++jt) {
    const int j0 = jt * 64;

    floatx4 acc[2];
#pragma unroll
    for (int n = 0; n < 2; ++n) acc[n] = (floatx4){0.f, 0.f, 0.f, 0.f};

#pragma unroll
    for (int ks = 0; ks < 2; ++ks) {
      int kof = ks * 32 + quad * 8;
#pragma unroll
      for (int n = 0; n < 2; ++n) {
        short8 bv = *(const short8*)&sXj[(ng * 2 + n) * 16 + la][kof];
        acc[n] = __builtin_amdgcn_mfma_f32_16x16x32_bf16(afrag[ks], bv, acc[n], 0, 0, 0);
      }
    }

    if (jt == 0) {
      // dense: capacity == tile width, slot = jl
#pragma unroll
      for (int n = 0; n < 2; ++n) {
        int jl = (ng * 2 + n) * 16 + la;
        float dj = sSqj[jl];
        uint32 jg = (uint32)(j0 + jl);
#pragma unroll
        for (int rg = 0; rg < 4; ++rg) {
          int il = mw * 16 + quad * 4 + rg;
          float d = fmaxf(sqa[rg] + dj - 2.0f * acc[n][rg], 0.f);
          sCand[il][jl] = (__float_as_uint(d) & 0xFFFFF800u) | jg;
        }
      }
    } else {
      uint32 tv[4];
      {
        uint4 u = *(const uint4*)&sTau[mw * 16 + quad * 4];
        tv[0] = u.x; tv[1] = u.y; tv[2] = u.z; tv[3] = u.w;
      }
#pragma unroll
      for (int n = 0; n < 2; ++n) {
        int jl = (ng * 2 + n) * 16 + la;
        float dj = sSqj[jl];
        uint32 jg = (uint32)(j0 + jl);
#pragma unroll
        for (int rg = 0; rg < 4; ++rg) {
          int il = mw * 16 + quad * 4 + rg;
          float d = fmaxf(sqa[rg] + dj - 2.0f * acc[n][rg], 0.f);
          uint32 key = (__float_as_uint(d) & 0xFFFFF800u) | jg;
          if (key < tv[rg]) {
            uint32 slot = atomicAdd(&sCnt[il], 1u);
            sCand[il][slot] = key;     // slot < 64 always (<=64 cands/row/tile)
          }
        }
      }
    }
    __syncthreads();

    // owner scan: waves 0-1, 4 threads/row over compacted survivors
    if (t < 128) {
      int cnt = (jt == 0) ? 64 : (int)sCnt[pp];
      for (int q = ss; q < cnt; q += 4) {
        uint32 cur = sCand[pp][q];
#pragma unroll
        for (int s = 0; s < KK; ++s) {
          uint32 lo = min(lst[s], cur);
          cur = max(lst[s], cur);
          lst[s] = lo;
        }
      }
      uint32 m19 = lst[KK - 1];
      m19 = min(m19, (uint32)__shfl_xor((int)m19, 1));
      m19 = min(m19, (uint32)__shfl_xor((int)m19, 2));
      if (ss == 0) { sTau[pp] = m19; sCnt[pp] = 0u; }
    }

    // prefetch next j-tile
    if (jt < 31) {
      const int jn = (jt + 1) * 64;
      int r = t >> 2, co = (t & 3) * 16;
      const ushortT* src = xbb + (size_t)(jn + r) * CC + co;
      *(uint4*)&sXj[r][co]     = *(const uint4*)(src);
      *(uint4*)&sXj[r][co + 8] = *(const uint4*)(src + 8);
      if (t < 64) sSqj[t] = sq[b * NN + jn + t];
    }
    __syncthreads();
  }

  if (t < 128) {
    size_t base = ((size_t)(b * NN + i0 + pp)) * 80 + ss * KK;
#pragma unroll
    for (int s = 0; s < KK; ++s) cand[base + s] = (ushortT)(lst[s] & 2047u);
  }
}

// ---------------------------------------------------------------- K1b: exact f64 rerank (unchanged, round-11 passing form)
__launch_bounds__(256, 4)
__global__ void k_rerank(const float* __restrict__ x, const ushortT* __restrict__ cand,
                         int* __restrict__ idxout) {
  const int b  = blockIdx.y;
  const int i0 = blockIdx.x * 16;
  const int t  = threadIdx.x;
  const int grp = t >> 4, lg = t & 15;

  __shared__ double sK[16][81];

  const float* xb = x + ((size_t)b * NN) * CC;
  const int p = i0 + grp;
  float4 vi = ((const float4*)(xb + (size_t)p * CC))[lg];
  size_t cb = ((size_t)(b * NN + p)) * 80;

  const bool hi8 = (lg & 8) != 0;
  const bool hi4 = (lg & 4) != 0;
  const bool hi2 = (lg & 2) != 0;
  const int  uslot = ((lg >> 1) & 1) | (((lg >> 2) & 1) << 1) | (((lg >> 3) & 1) << 2);

  for (int q0 = 0; q0 < 80; q0 += 8) {
    int jj0 = (int)cand[cb + q0 + 0], jj1 = (int)cand[cb + q0 + 1];
    int jj2 = (int)cand[cb + q0 + 2], jj3 = (int)cand[cb + q0 + 3];
    int jj4 = (int)cand[cb + q0 + 4], jj5 = (int)cand[cb + q0 + 5];
    int jj6 = (int)cand[cb + q0 + 6], jj7 = (int)cand[cb + q0 + 7];

#define DISTQ(JJ, DD)                                                        \
    double DD;                                                               \
    {                                                                        \
      float4 vj = ((const float4*)(xb + (size_t)(JJ) * CC))[lg];             \
      double e0 = (double)vi.x - (double)vj.x;                               \
      double e1 = (double)vi.y - (double)vj.y;                               \
      double e2 = (double)vi.z - (double)vj.z;                               \
      double e3 = (double)vi.w - (double)vj.w;                               \
      DD = e0 * e0 + e1 * e1 + e2 * e2 + e3 * e3;                            \
    }
    DISTQ(jj0, dd0) DISTQ(jj1, dd1) DISTQ(jj2, dd2) DISTQ(jj3, dd3)
    DISTQ(jj4, dd4) DISTQ(jj5, dd5) DISTQ(jj6, dd6) DISTQ(jj7, dd7)
#undef DISTQ

    double m0 = hi8 ? dd4 : dd0, s0 = hi8 ? dd0 : dd4;
    double m1 = hi8 ? dd5 : dd1, s1 = hi8 ? dd1 : dd5;
    double m2 = hi8 ? dd6 : dd2, s2 = hi8 ? dd2 : dd6;
    double m3 = hi8 ? dd7 : dd3, s3 = hi8 ? dd3 : dd7;
    double r40 = m0 + __shfl_xor(s0, 8, 16);
    double r41 = m1 + __shfl_xor(s1, 8, 16);
    double r42 = m2 + __shfl_xor(s2, 8, 16);
    double r43 = m3 + __shfl_xor(s3, 8, 16);
    int j40 = hi8 ? jj4 : jj0, j41 = hi8 ? jj5 : jj1;
    int j42 = hi8 ? jj6 : jj2, j43 = hi8 ? jj7 : jj3;

    double n0 = hi4 ? r42 : r40, t0 = hi4 ? r40 : r42;
    double n1 = hi4 ? r43 : r41, t1 = hi4 ? r41 : r43;
    double r20 = n0 + __shfl_xor(t0, 4, 16);
    double r21 = n1 + __shfl_xor(t1, 4, 16);
    int j20 = hi4 ? j42 : j40, j21 = hi4 ? j43 : j41;

    double p0 = hi2 ? r21 : r20, u0 = hi2 ? r20 : r21;
    double r1 = p0 + __shfl_xor(u0, 2, 16);
    int j1 = hi2 ? j21 : j20;

    r1 += __shfl_xor(r1, 1, 16);

    if ((lg & 1) == 0) {
      uint64 bits = (uint64)__double_as_longlong(r1);   // d >= 0: order-preserving
      sK[grp][q0 + uslot] = __longlong_as_double((bits & ~2047ULL) | (uint64)j1);
    }
  }
  __syncthreads();

  double k5[5];
#pragma unroll
  for (int s = 0; s < 5; ++s) k5[s] = sK[grp][lg + 16 * s];

  const double DINF = __longlong_as_double(0x7FF0000000000000LL);
  size_t obase = ((size_t)(b * NN + p)) * KK;
  for (int r = 0; r < KK; ++r) {
    double lm = fmin(fmin(fmin(k5[0], k5[1]), fmin(k5[2], k5[3])), k5[4]);
#pragma unroll
    for (int off = 8; off > 0; off >>= 1)
      lm = fmin(lm, __shfl_xor(lm, off, 16));
#pragma unroll
    for (int s = 0; s < 5; ++s) k5[s] = (k5[s] == lm) ? DINF : k5[s];
    if (lg == (r & 15))
      idxout[obase + r] = (int)((uint64)__double_as_longlong(lm) & 2047ULL);
  }
}

// ---------------------------------------------------------------- K2: edge MLP + max-agg (unchanged)
__launch_bounds__(256, 4)
__global__ void k_mlp(const float* __restrict__ x, const ushortT* __restrict__ xbf,
                      const int* __restrict__ idx, const ushortT* __restrict__ wbf,
                      const float* __restrict__ b1, const float* __restrict__ b2,
                      const float* __restrict__ b3, float* __restrict__ agg) {
  const int b  = blockIdx.y;
  const int i0 = blockIdx.x * 4;
  const int t  = threadIdx.x;
  const int l  = t & 63, wv = t >> 6;
  const int la = l & 15, quad = l >> 4;

  __shared__ __align__(16) char sm[35008];
  ushortT (*sDH)[68]  = (ushortT(*)[68])(sm + 0);
  ushortT (*sDL)[68]  = (ushortT(*)[68])(sm + 10880);
  ushortT (*sH1)[68]  = (ushortT(*)[68])(sm + 21760);
  float   (*sPre)[64] = (float(*)[64])(sm + 32640);
  uint32*  sAgg       = (uint32*)(sm + 33664);
  int*     sJ         = (int*)(sm + 34688);
  ushortT (*sH2)[68]  = sDH;

  const int c = wv * 16 + la;
  const ushortT* w1aT = wbf;
  const ushortT* w1bT = wbf + 4096;
  const ushortT* w2T  = wbf + 8192;
  const ushortT* w3T  = wbf + 12288;

  if (t < 80) {
    int p = t / 20, kk = t - p * 20;
    int v = idx[((size_t)(b * NN + i0 + p)) * KK + kk];
    v = v < 0 ? 0 : (v > (NN - 1) ? (NN - 1) : v);
    sJ[t] = v;
  }
  sAgg[t] = 0u;

  float b2c = b2[c], b3c = b3[c];

  {
    float b1c = b1[c];
    floatx4 ap = (floatx4){b1c, b1c, b1c, b1c};
#pragma unroll
    for (int ks = 0; ks < 2; ++ks) {
      short8 av = *(const short8*)(xbf + (size_t)(b * NN + i0 + (la & 3)) * CC + ks * 32 + quad * 8);
      short8 bv = *(const short8*)(w1aT + c * 64 + ks * 32 + quad * 8);
      ap = __builtin_amdgcn_mfma_f32_16x16x32_bf16(av, bv, ap, 0, 0, 0);
    }
    if (quad == 0) {
#pragma unroll
      for (int rg = 0; rg < 4; ++rg) sPre[rg][c] = ap[rg];
    }
  }
  __syncthreads();

  const float* xb = x + ((size_t)b * NN) * CC;
  for (int e = t; e < 1280; e += 256) {
    int r = e >> 4, c4g = e & 15, c4 = c4g * 4;
    int p = r / 20;
    float4 vi = ((const float4*)(xb + (size_t)(i0 + p) * CC))[c4g];
    float4 vj = ((const float4*)(xb + (size_t)sJ[r] * CC))[c4g];
    short4v dh, dl;
    ushortT hh, ll;
    split2(vj.x - vi.x, hh, ll); dh.x = (short)hh; dl.x = (short)ll;
    split2(vj.y - vi.y, hh, ll); dh.y = (short)hh; dl.y = (short)ll;
    split2(vj.z - vi.z, hh, ll); dh.z = (short)hh; dl.z = (short)ll;
    split2(vj.w - vi.w, hh, ll); dh.w = (short)hh; dl.w = (short)ll;
    *(short4v*)&sDH[r][c4] = dh;
    *(short4v*)&sDL[r][c4] = dl;
  }
  __syncthreads();

  {
    short8 bB[2];
#pragma unroll
    for (int ks = 0; ks < 2; ++ks)
      bB[ks] = *(const short8*)(w1bT + c * 64 + ks * 32 + quad * 8);
#pragma unroll
    for (int m5 = 0; m5 < 5; ++m5) {
      floatx4 a;
#pragma unroll
      for (int rg = 0; rg < 4; ++rg) {
        int r = m5 * 16 + quad * 4 + rg;
        a[rg] = sPre[r / 20][c];
      }
#pragma unroll
      for (int ks = 0; ks < 2; ++ks) {
        int kof = ks * 32 + quad * 8;
        short8 aDH = ld8(&sDH[m5 * 16 + la][kof]);
        short8 aDL = ld8(&sDL[m5 * 16 + la][kof]);
        a = __builtin_amdgcn_mfma_f32_16x16x32_bf16(aDH, bB[ks], a, 0, 0, 0);
        a = __builtin_amdgcn_mfma_f32_16x16x32_bf16(aDL, bB[ks], a, 0, 0, 0);
      }
#pragma unroll
      for (int rg = 0; rg < 4; ++rg) {
        int r = m5 * 16 + quad * 4 + rg;
        sH1[r][c] = f2bf(fmaxf(a[rg], 0.f));
      }
    }
  }
  __syncthreads();

  {
    short8 bf[2];
#pragma unroll
    for (int ks = 0; ks < 2; ++ks)
      bf[ks] = *(const short8*)(w2T + c * 64 + ks * 32 + quad * 8);
#pragma unroll
    for (int m5 = 0; m5 < 5; ++m5) {
      floatx4 a = (floatx4){b2c, b2c, b2c, b2c};
#pragma unroll
      for (int ks = 0; ks < 2; ++ks) {
        short8 aH = ld8(&sH1[m5 * 16 + la][ks * 32 + quad * 8]);
        a = __builtin_amdgcn_mfma_f32_16x16x32_bf16(aH, bf[ks], a, 0, 0, 0);
      }
#pragma unroll
      for (int rg = 0; rg < 4; ++rg) {
        int r = m5 * 16 + quad * 4 + rg;
        sH2[r][c] = f2bf(fmaxf(a[rg], 0.f));
      }
    }
  }
  __syncthreads();

  {
    short8 bf[2];
#pragma unroll
    for (int ks = 0; ks < 2; ++ks)
      bf[ks] = *(const short8*)(w3T + c * 64 + ks * 32 + quad * 8);
#pragma unroll
    for (int m5 = 0; m5 < 5; ++m5) {
      floatx4 a = (floatx4){b3c, b3c, b3c, b3c};
#pragma unroll
      for (int ks = 0; ks < 2; ++ks) {
        short8 aH = ld8(&sH2[m5 * 16 + la][ks * 32 + quad * 8]);
        a = __builtin_amdgcn_mfma_f32_16x16x32_bf16(aH, bf[ks], a, 0, 0, 0);
      }
#pragma unroll
      for (int rg = 0; rg < 4; ++rg) {
        int r = m5 * 16 + quad * 4 + rg;
        int p = r / 20;
        atomicMax(&sAgg[p * 64 + c], fmap(a[rg]));
      }
    }
  }
  __syncthreads();

  {
    int p = t >> 6, cc = t & 63;
    agg[((size_t)(b * NN + i0 + p)) * CC + cc] = funmap(sAgg[t]);
  }
}

// ---------------------------------------------------------------- K3a: SE partial sums (256 blocks)
// Replaces 16-block k_se front: each block sums 128 rows x 64 ch.
__global__ void k_se1(const float* __restrict__ agg, float* __restrict__ part) {
  int b = blockIdx.x >> 4, ch = blockIdx.x & 15;
  int t = threadIdx.x;
  int c = t & 63, q = t >> 6;
  __shared__ float red[4][64];
  const float* ab = agg + ((size_t)(b * NN) + ch * 128) * CC;
  float s = 0.f;
  for (int r = q * 32; r < q * 32 + 32; ++r) s += ab[(size_t)r * CC + c];
  red[q][c] = s;
  __syncthreads();
  if (t < 64)
    part[blockIdx.x * 64 + t] = (red[0][t] + red[1][t]) + (red[2][t] + red[3][t]);
}

// ---------------------------------------------------------------- K3b: SE finish (16 blocks x 64)
__global__ void k_se2(const float* __restrict__ part, const float* __restrict__ sew1,
                      const float* __restrict__ sew2, float* __restrict__ y) {
  int b = blockIdx.x, t = threadIdx.x;
  __shared__ float sv[64];
  __shared__ float hid[4];
  {
    float s = 0.f;
#pragma unroll
    for (int k = 0; k < 16; ++k) s += part[(b * 16 + k) * 64 + t];
    sv[t] = s * (1.f / 2048.f);
  }
  __syncthreads();
  if (t < 4) {
    float a = 0.f;
    for (int cc = 0; cc < 64; ++cc) a += sv[cc] * sew1[cc * 4 + t];
    hid[t] = fmaxf(a, 0.f);
  }
  __syncthreads();
  {
    float a = 0.f;
#pragma unroll
    for (int h = 0; h < 4; ++h) a += hid[h] * sew2[h * 64 + t];
    y[b * 64 + t] = 1.f / (1.f + expf(-a));
  }
}

// ---------------------------------------------------------------- K4: per-point stats (f32)
__global__ void k_stats(const float* __restrict__ agg, const float* __restrict__ y,
                        float* __restrict__ ycat) {
  int t = threadIdx.x;
  int gid = blockIdx.x * 4 + (t >> 6);
  int l = t & 63;
  int b = gid >> 11, i = gid & 2047;
  float v = agg[(size_t)gid * CC + l] * y[b * 64 + l];
  float s = v, mx = v;
#pragma unroll
  for (int off = 32; off > 0; off >>= 1) {
    s += __shfl_xor(s, off);
    mx = fmaxf(mx, __shfl_xor(mx, off));
  }
  if (l == 0) {
    ycat[b * 2 * NN + i] = s * (1.f / 64.f);
    ycat[b * 2 * NN + NN + i] = mx;
  }
}

// ---------------------------------------------------------------- K5: conv7 att + add (f32 out)
__global__ void k_final(const float* __restrict__ agg, const float* __restrict__ y,
                        const float* __restrict__ ycat, const float* __restrict__ saw,
                        const float* __restrict__ x, float* __restrict__ out) {
  int e = blockIdx.x * 256 + threadIdx.x;
  int ifl = e >> 6, c = e & 63;
  int b = ifl >> 11, i = ifl & 2047;
  float a = 0.f;
#pragma unroll
  for (int w = 0; w < 7; ++w) {
    int ii = i + w - 3;
    if (ii >= 0 && ii < NN) {
      a += ycat[b * 2 * NN + ii] * saw[w];
      a += ycat[b * 2 * NN + NN + ii] * saw[7 + w];
    }
  }
  float att = 1.f / (1.f + expf(-a));
  out[e] = agg[(size_t)ifl * CC + c] * y[b * 64 + c] * att + x[(size_t)e];
}

// ----------------------------------------------------------------
extern "C" void kernel_launch(void* const* d_in, const int* in_sizes, int n_in,
                              void* d_out, int out_size, void* d_ws, size_t ws_size,
                              hipStream_t stream) {
  const float* x    = (const float*)d_in[0];
  const float* w1   = (const float*)d_in[3];
  const float* b1   = (const float*)d_in[4];
  const float* w2   = (const float*)d_in[5];
  const float* b2   = (const float*)d_in[6];
  const float* w3   = (const float*)d_in[7];
  const float* b3   = (const float*)d_in[8];
  const float* sew1 = (const float*)d_in[9];
  const float* sew2 = (const float*)d_in[10];
  const float* saw  = (const float*)d_in[11];
  float* out = (float*)d_out;

  char* ws = (char*)d_ws;
  float*   sq   = (float*)  (ws);                          // 131072 B
  int*     idx  = (int*)    (ws + 131072);                 // 2621440 B
  float*   part = (float*)  (ws + 131072);                 // 65536 B (aliases idx; idx is
                                                           // consumed by k_mlp before k_se1)
  ushortT* cand = (ushortT*)(ws + 2752512);                // 5242880 B (32768*80 u16)
  float*   agg  = (float*)  (ws + 2752512);                // 8388608 B (aliases cand; cand
                                                           // consumed before k_mlp writes)
  float*   y    = (float*)  (ws + 11141120);               // 4096 B
  float*   ycat = (float*)  (ws + 11145216);               // 262144 B
  ushortT* wbf  = (ushortT*)(ws + 11407360);               // 32768 B -> total 11440128 B

  // bf16 image of x lives in d_out (4 MB of its 8 MB) until k_final overwrites it.
  ushortT* xbf = (ushortT*)d_out;

  k_wconv <<<1,              256, 0, stream>>>(w1, w2, w3, wbf);
  k_sq    <<<128,            256, 0, stream>>>(x, sq, xbf);
  k_knn   <<<dim3(64, 16),   256, 0, stream>>>(xbf, sq, cand);
  k_rerank<<<dim3(128, 16),  256, 0, stream>>>(x, cand, idx);
  k_mlp   <<<dim3(512, 16),  256, 0, stream>>>(x, xbf, idx, wbf, b1, b2, b3, agg);
  k_se1   <<<256,            256, 0, stream>>>(agg, part);
  k_se2   <<<16,             64,  0, stream>>>(part, sew1, sew2, y);
  k_stats <<<8192,           256, 0, stream>>>(agg, y, ycat);
  k_final <<<8192,           256, 0, stream>>>(agg, y, ycat, saw, x, out);
}

// Round 13
// 326.070 us; speedup vs baseline: 1.1102x; 1.1102x over previous
//
#include <hip/hip_runtime.h>

typedef unsigned int uint32;
typedef unsigned long long uint64;
typedef unsigned short ushortT;
typedef __attribute__((ext_vector_type(8))) short short8;
typedef __attribute__((ext_vector_type(4))) short short4v;
typedef __attribute__((ext_vector_type(4))) float floatx4;

#define DEV static __device__ __forceinline__

#define NN 2048
#define CC 64
#define KK 20

DEV float bf2f(ushortT h) {
  union { uint32 u; float f; } c; c.u = ((uint32)h) << 16; return c.f;
}
DEV ushortT f2bf(float f) {
  union { float f; uint32 u; } c; c.f = f;
  uint32 r = c.u + 0x7FFFu + ((c.u >> 16) & 1u);   // RNE
  return (ushortT)(r >> 16);
}
DEV void split2(float v, ushortT& h, ushortT& l) {
  h = f2bf(v);
  l = f2bf(v - bf2f(h));
}
DEV uint32 fmap(float f) {            // monotone f32 -> u32
  uint32 u = __float_as_uint(f);
  return (u & 0x80000000u) ? ~u : (u | 0x80000000u);
}
DEV float funmap(uint32 m) {
  uint32 u = (m & 0x80000000u) ? (m ^ 0x80000000u) : ~m;
  return __uint_as_float(u);
}
DEV short8 ld8(const ushortT* p) {    // 8B-aligned 16B load as two b64
  short4v a = *(const short4v*)p;
  short4v b = *(const short4v*)(p + 4);
  short8 r;
  r[0] = a.x; r[1] = a.y; r[2] = a.z; r[3] = a.w;
  r[4] = b.x; r[5] = b.y; r[6] = b.z; r[7] = b.w;
  return r;
}

// ---------------------------------------------------------------- K0: sq norms + bf16 image of x
__global__ void k_sq(const float* __restrict__ x, float* __restrict__ sq,
                     ushortT* __restrict__ xbf) {
  int p = blockIdx.x * 256 + threadIdx.x;
  const float4* row = (const float4*)(x + (size_t)p * CC);
  ushortT* orow = xbf + (size_t)p * CC;
  float s = 0.f;
#pragma unroll
  for (int q = 0; q < 16; ++q) {
    float4 v = row[q];
    s += v.x * v.x + v.y * v.y + v.z * v.z + v.w * v.w;
    short4v h;
    h.x = (short)f2bf(v.x); h.y = (short)f2bf(v.y);
    h.z = (short)f2bf(v.z); h.w = (short)f2bf(v.w);
    *(short4v*)(orow + q * 4) = h;
  }
  sq[p] = s;
}

// ---------------------------------------------------------------- K0b: one-time weight transpose+bf16
__global__ void k_wconv(const float* __restrict__ w1, const float* __restrict__ w2,
                        const float* __restrict__ w3, ushortT* __restrict__ wbf) {
  int t = threadIdx.x;
  for (int e = t; e < 4096; e += 256) {
    int n = e >> 6, k = e & 63;
    wbf[e]         = f2bf(w1[k * 64 + n]);
    wbf[4096 + e]  = f2bf(w1[(64 + k) * 64 + n]);
    wbf[8192 + e]  = f2bf(w2[k * 64 + n]);
    wbf[12288 + e] = f2bf(w3[k * 64 + n]);
  }
}

// ---------------------------------------------------------------- K1: KNN stage 1
// 64-wide j-tiles (LDS 18.3KB) + launch_bounds(256,6): VGPR budget 85 holds
// the ~60-reg live set (lst[20] ladder + frags) WITHOUT spill; round-12's
// (256,8) forced a 64-VGPR budget -> ladder spilled (VGPR=32, 22MB scratch
// writes, 137us). 6 blocks/CU = 24 waves/CU vs round-11's 16. sCand capacity
// == tile width (64): overflow impossible by construction.
__launch_bounds__(256, 6)
__global__ void k_knn(const ushortT* __restrict__ xbf, const float* __restrict__ sq,
                      ushortT* __restrict__ cand) {
  const int b  = blockIdx.y;
  const int i0 = blockIdx.x * 32;
  const int t  = threadIdx.x;
  const int l  = t & 63, wv = t >> 6;
  const int la = l & 15, quad = l >> 4;
  const int pp = t >> 2, ss = t & 3;     // owners: t<128 -> rows 0..31

  __shared__ __align__(16) char sm[18304];
  ushortT (*sXj)[72]   = (ushortT(*)[72])(sm);           // 9216 B
  uint32  (*sCand)[66] = (uint32(*)[66])(sm + 9216);     // 8448 B -> 17664
  uint32*  sTau        = (uint32*)(sm + 17664);          // 128 B -> 17792
  uint32*  sCnt        = (uint32*)(sm + 17792);          // 128 B -> 17920
  float*   sSqi        = (float*)(sm + 17920);           // 128 B -> 18048
  float*   sSqj        = (float*)(sm + 18048);           // 256 B -> 18304

  const ushortT* xbb = xbf + ((size_t)b * NN) * CC;

  const int mw = wv & 1;             // which 16-row m-tile of the 32
  const int ng = wv >> 1;            // n-group: j-rows ng*32 .. ng*32+31

  short8 afrag[2];
  {
    const ushortT* rowp = xbb + (size_t)(i0 + mw * 16 + la) * CC;
#pragma unroll
    for (int ks = 0; ks < 2; ++ks)
      afrag[ks] = *(const short8*)(rowp + ks * 32 + quad * 8);
  }
  if (t < 32) sSqi[t] = sq[b * NN + i0 + t];

  // stage tile 0: 64 rows, 4 threads/row, 16 shorts (2x uint4) each
  {
    int r = t >> 2, co = (t & 3) * 16;
    const ushortT* src = xbb + (size_t)r * CC + co;
    *(uint4*)&sXj[r][co]     = *(const uint4*)(src);
    *(uint4*)&sXj[r][co + 8] = *(const uint4*)(src + 8);
  }
  if (t < 64) sSqj[t] = sq[b * NN + t];

  uint32 lst[KK];
#pragma unroll
  for (int s = 0; s < KK; ++s) lst[s] = 0xFFFFFFFFu;

  __syncthreads();

  float sqa[4];
  {
    float4 v = *(const float4*)&sSqi[mw * 16 + quad * 4];
    sqa[0] = v.x; sqa[1] = v.y; sqa[2] = v.z; sqa[3] = v.w;
  }

  for (int jt = 0; jt < 32; ++jt) {
    const int j0 = jt * 64;

    floatx4 acc[2];
#pragma unroll
    for (int n = 0; n < 2; ++n) acc[n] = (floatx4){0.f, 0.f, 0.f, 0.f};

#pragma unroll
    for (int ks = 0; ks < 2; ++ks) {
      int kof = ks * 32 + quad * 8;
#pragma unroll
      for (int n = 0; n < 2; ++n) {
        short8 bv = *(const short8*)&sXj[(ng * 2 + n) * 16 + la][kof];
        acc[n] = __builtin_amdgcn_mfma_f32_16x16x32_bf16(afrag[ks], bv, acc[n], 0, 0, 0);
      }
    }

    if (jt == 0) {
      // dense: capacity == tile width, slot = jl
#pragma unroll
      for (int n = 0; n < 2; ++n) {
        int jl = (ng * 2 + n) * 16 + la;
        float dj = sSqj[jl];
        uint32 jg = (uint32)(j0 + jl);
#pragma unroll
        for (int rg = 0; rg < 4; ++rg) {
          int il = mw * 16 + quad * 4 + rg;
          float d = fmaxf(sqa[rg] + dj - 2.0f * acc[n][rg], 0.f);
          sCand[il][jl] = (__float_as_uint(d) & 0xFFFFF800u) | jg;
        }
      }
    } else {
      uint32 tv[4];
      {
        uint4 u = *(const uint4*)&sTau[mw * 16 + quad * 4];
        tv[0] = u.x; tv[1] = u.y; tv[2] = u.z; tv[3] = u.w;
      }
#pragma unroll
      for (int n = 0; n < 2; ++n) {
        int jl = (ng * 2 + n) * 16 + la;
        float dj = sSqj[jl];
        uint32 jg = (uint32)(j0 + jl);
#pragma unroll
        for (int rg = 0; rg < 4; ++rg) {
          int il = mw * 16 + quad * 4 + rg;
          float d = fmaxf(sqa[rg] + dj - 2.0f * acc[n][rg], 0.f);
          uint32 key = (__float_as_uint(d) & 0xFFFFF800u) | jg;
          if (key < tv[rg]) {
            uint32 slot = atomicAdd(&sCnt[il], 1u);
            sCand[il][slot] = key;     // slot < 64 always (<=64 cands/row/tile)
          }
        }
      }
    }
    __syncthreads();

    // owner scan: waves 0-1, 4 threads/row over compacted survivors
    if (t < 128) {
      int cnt = (jt == 0) ? 64 : (int)sCnt[pp];
      for (int q = ss; q < cnt; q += 4) {
        uint32 cur = sCand[pp][q];
#pragma unroll
        for (int s = 0; s < KK; ++s) {
          uint32 lo = min(lst[s], cur);
          cur = max(lst[s], cur);
          lst[s] = lo;
        }
      }
      uint32 m19 = lst[KK - 1];
      m19 = min(m19, (uint32)__shfl_xor((int)m19, 1));
      m19 = min(m19, (uint32)__shfl_xor((int)m19, 2));
      if (ss == 0) { sTau[pp] = m19; sCnt[pp] = 0u; }
    }

    // prefetch next j-tile
    if (jt < 31) {
      const int jn = (jt + 1) * 64;
      int r = t >> 2, co = (t & 3) * 16;
      const ushortT* src = xbb + (size_t)(jn + r) * CC + co;
      *(uint4*)&sXj[r][co]     = *(const uint4*)(src);
      *(uint4*)&sXj[r][co + 8] = *(const uint4*)(src + 8);
      if (t < 64) sSqj[t] = sq[b * NN + jn + t];
    }
    __syncthreads();
  }

  if (t < 128) {
    size_t base = ((size_t)(b * NN + i0 + pp)) * 80 + ss * KK;
#pragma unroll
    for (int s = 0; s < KK; ++s) cand[base + s] = (ushortT)(lst[s] & 2047u);
  }
}

// ---------------------------------------------------------------- K1b: exact f64 rerank (unchanged, round-11 passing form)
__launch_bounds__(256, 4)
__global__ void k_rerank(const float* __restrict__ x, const ushortT* __restrict__ cand,
                         int* __restrict__ idxout) {
  const int b  = blockIdx.y;
  const int i0 = blockIdx.x * 16;
  const int t  = threadIdx.x;
  const int grp = t >> 4, lg = t & 15;

  __shared__ double sK[16][81];

  const float* xb = x + ((size_t)b * NN) * CC;
  const int p = i0 + grp;
  float4 vi = ((const float4*)(xb + (size_t)p * CC))[lg];
  size_t cb = ((size_t)(b * NN + p)) * 80;

  const bool hi8 = (lg & 8) != 0;
  const bool hi4 = (lg & 4) != 0;
  const bool hi2 = (lg & 2) != 0;
  const int  uslot = ((lg >> 1) & 1) | (((lg >> 2) & 1) << 1) | (((lg >> 3) & 1) << 2);

  for (int q0 = 0; q0 < 80; q0 += 8) {
    int jj0 = (int)cand[cb + q0 + 0], jj1 = (int)cand[cb + q0 + 1];
    int jj2 = (int)cand[cb + q0 + 2], jj3 = (int)cand[cb + q0 + 3];
    int jj4 = (int)cand[cb + q0 + 4], jj5 = (int)cand[cb + q0 + 5];
    int jj6 = (int)cand[cb + q0 + 6], jj7 = (int)cand[cb + q0 + 7];

#define DISTQ(JJ, DD)                                                        \
    double DD;                                                               \
    {                                                                        \
      float4 vj = ((const float4*)(xb + (size_t)(JJ) * CC))[lg];             \
      double e0 = (double)vi.x - (double)vj.x;                               \
      double e1 = (double)vi.y - (double)vj.y;                               \
      double e2 = (double)vi.z - (double)vj.z;                               \
      double e3 = (double)vi.w - (double)vj.w;                               \
      DD = e0 * e0 + e1 * e1 + e2 * e2 + e3 * e3;                            \
    }
    DISTQ(jj0, dd0) DISTQ(jj1, dd1) DISTQ(jj2, dd2) DISTQ(jj3, dd3)
    DISTQ(jj4, dd4) DISTQ(jj5, dd5) DISTQ(jj6, dd6) DISTQ(jj7, dd7)
#undef DISTQ

    double m0 = hi8 ? dd4 : dd0, s0 = hi8 ? dd0 : dd4;
    double m1 = hi8 ? dd5 : dd1, s1 = hi8 ? dd1 : dd5;
    double m2 = hi8 ? dd6 : dd2, s2 = hi8 ? dd2 : dd6;
    double m3 = hi8 ? dd7 : dd3, s3 = hi8 ? dd3 : dd7;
    double r40 = m0 + __shfl_xor(s0, 8, 16);
    double r41 = m1 + __shfl_xor(s1, 8, 16);
    double r42 = m2 + __shfl_xor(s2, 8, 16);
    double r43 = m3 + __shfl_xor(s3, 8, 16);
    int j40 = hi8 ? jj4 : jj0, j41 = hi8 ? jj5 : jj1;
    int j42 = hi8 ? jj6 : jj2, j43 = hi8 ? jj7 : jj3;

    double n0 = hi4 ? r42 : r40, t0 = hi4 ? r40 : r42;
    double n1 = hi4 ? r43 : r41, t1 = hi4 ? r41 : r43;
    double r20 = n0 + __shfl_xor(t0, 4, 16);
    double r21 = n1 + __shfl_xor(t1, 4, 16);
    int j20 = hi4 ? j42 : j40, j21 = hi4 ? j43 : j41;

    double p0 = hi2 ? r21 : r20, u0 = hi2 ? r20 : r21;
    double r1 = p0 + __shfl_xor(u0, 2, 16);
    int j1 = hi2 ? j21 : j20;

    r1 += __shfl_xor(r1, 1, 16);

    if ((lg & 1) == 0) {
      uint64 bits = (uint64)__double_as_longlong(r1);   // d >= 0: order-preserving
      sK[grp][q0 + uslot] = __longlong_as_double((bits & ~2047ULL) | (uint64)j1);
    }
  }
  __syncthreads();

  double k5[5];
#pragma unroll
  for (int s = 0; s < 5; ++s) k5[s] = sK[grp][lg + 16 * s];

  const double DINF = __longlong_as_double(0x7FF0000000000000LL);
  size_t obase = ((size_t)(b * NN + p)) * KK;
  for (int r = 0; r < KK; ++r) {
    double lm = fmin(fmin(fmin(k5[0], k5[1]), fmin(k5[2], k5[3])), k5[4]);
#pragma unroll
    for (int off = 8; off > 0; off >>= 1)
      lm = fmin(lm, __shfl_xor(lm, off, 16));
#pragma unroll
    for (int s = 0; s < 5; ++s) k5[s] = (k5[s] == lm) ? DINF : k5[s];
    if (lg == (r & 15))
      idxout[obase + r] = (int)((uint64)__double_as_longlong(lm) & 2047ULL);
  }
}

// ---------------------------------------------------------------- K2: edge MLP + max-agg (unchanged)
__launch_bounds__(256, 4)
__global__ void k_mlp(const float* __restrict__ x, const ushortT* __restrict__ xbf,
                      const int* __restrict__ idx, const ushortT* __restrict__ wbf,
                      const float* __restrict__ b1, const float* __restrict__ b2,
                      const float* __restrict__ b3, float* __restrict__ agg) {
  const int b  = blockIdx.y;
  const int i0 = blockIdx.x * 4;
  const int t  = threadIdx.x;
  const int l  = t & 63, wv = t >> 6;
  const int la = l & 15, quad = l >> 4;

  __shared__ __align__(16) char sm[35008];
  ushortT (*sDH)[68]  = (ushortT(*)[68])(sm + 0);
  ushortT (*sDL)[68]  = (ushortT(*)[68])(sm + 10880);
  ushortT (*sH1)[68]  = (ushortT(*)[68])(sm + 21760);
  float   (*sPre)[64] = (float(*)[64])(sm + 32640);
  uint32*  sAgg       = (uint32*)(sm + 33664);
  int*     sJ         = (int*)(sm + 34688);
  ushortT (*sH2)[68]  = sDH;

  const int c = wv * 16 + la;
  const ushortT* w1aT = wbf;
  const ushortT* w1bT = wbf + 4096;
  const ushortT* w2T  = wbf + 8192;
  const ushortT* w3T  = wbf + 12288;

  if (t < 80) {
    int p = t / 20, kk = t - p * 20;
    int v = idx[((size_t)(b * NN + i0 + p)) * KK + kk];
    v = v < 0 ? 0 : (v > (NN - 1) ? (NN - 1) : v);
    sJ[t] = v;
  }
  sAgg[t] = 0u;

  float b2c = b2[c], b3c = b3[c];

  {
    float b1c = b1[c];
    floatx4 ap = (floatx4){b1c, b1c, b1c, b1c};
#pragma unroll
    for (int ks = 0; ks < 2; ++ks) {
      short8 av = *(const short8*)(xbf + (size_t)(b * NN + i0 + (la & 3)) * CC + ks * 32 + quad * 8);
      short8 bv = *(const short8*)(w1aT + c * 64 + ks * 32 + quad * 8);
      ap = __builtin_amdgcn_mfma_f32_16x16x32_bf16(av, bv, ap, 0, 0, 0);
    }
    if (quad == 0) {
#pragma unroll
      for (int rg = 0; rg < 4; ++rg) sPre[rg][c] = ap[rg];
    }
  }
  __syncthreads();

  const float* xb = x + ((size_t)b * NN) * CC;
  for (int e = t; e < 1280; e += 256) {
    int r = e >> 4, c4g = e & 15, c4 = c4g * 4;
    int p = r / 20;
    float4 vi = ((const float4*)(xb + (size_t)(i0 + p) * CC))[c4g];
    float4 vj = ((const float4*)(xb + (size_t)sJ[r] * CC))[c4g];
    short4v dh, dl;
    ushortT hh, ll;
    split2(vj.x - vi.x, hh, ll); dh.x = (short)hh; dl.x = (short)ll;
    split2(vj.y - vi.y, hh, ll); dh.y = (short)hh; dl.y = (short)ll;
    split2(vj.z - vi.z, hh, ll); dh.z = (short)hh; dl.z = (short)ll;
    split2(vj.w - vi.w, hh, ll); dh.w = (short)hh; dl.w = (short)ll;
    *(short4v*)&sDH[r][c4] = dh;
    *(short4v*)&sDL[r][c4] = dl;
  }
  __syncthreads();

  {
    short8 bB[2];
#pragma unroll
    for (int ks = 0; ks < 2; ++ks)
      bB[ks] = *(const short8*)(w1bT + c * 64 + ks * 32 + quad * 8);
#pragma unroll
    for (int m5 = 0; m5 < 5; ++m5) {
      floatx4 a;
#pragma unroll
      for (int rg = 0; rg < 4; ++rg) {
        int r = m5 * 16 + quad * 4 + rg;
        a[rg] = sPre[r / 20][c];
      }
#pragma unroll
      for (int ks = 0; ks < 2; ++ks) {
        int kof = ks * 32 + quad * 8;
        short8 aDH = ld8(&sDH[m5 * 16 + la][kof]);
        short8 aDL = ld8(&sDL[m5 * 16 + la][kof]);
        a = __builtin_amdgcn_mfma_f32_16x16x32_bf16(aDH, bB[ks], a, 0, 0, 0);
        a = __builtin_amdgcn_mfma_f32_16x16x32_bf16(aDL, bB[ks], a, 0, 0, 0);
      }
#pragma unroll
      for (int rg = 0; rg < 4; ++rg) {
        int r = m5 * 16 + quad * 4 + rg;
        sH1[r][c] = f2bf(fmaxf(a[rg], 0.f));
      }
    }
  }
  __syncthreads();

  {
    short8 bf[2];
#pragma unroll
    for (int ks = 0; ks < 2; ++ks)
      bf[ks] = *(const short8*)(w2T + c * 64 + ks * 32 + quad * 8);
#pragma unroll
    for (int m5 = 0; m5 < 5; ++m5) {
      floatx4 a = (floatx4){b2c, b2c, b2c, b2c};
#pragma unroll
      for (int ks = 0; ks < 2; ++ks) {
        short8 aH = ld8(&sH1[m5 * 16 + la][ks * 32 + quad * 8]);
        a = __builtin_amdgcn_mfma_f32_16x16x32_bf16(aH, bf[ks], a, 0, 0, 0);
      }
#pragma unroll
      for (int rg = 0; rg < 4; ++rg) {
        int r = m5 * 16 + quad * 4 + rg;
        sH2[r][c] = f2bf(fmaxf(a[rg], 0.f));
      }
    }
  }
  __syncthreads();

  {
    short8 bf[2];
#pragma unroll
    for (int ks = 0; ks < 2; ++ks)
      bf[ks] = *(const short8*)(w3T + c * 64 + ks * 32 + quad * 8);
#pragma unroll
    for (int m5 = 0; m5 < 5; ++m5) {
      floatx4 a = (floatx4){b3c, b3c, b3c, b3c};
#pragma unroll
      for (int ks = 0; ks < 2; ++ks) {
        short8 aH = ld8(&sH2[m5 * 16 + la][ks * 32 + quad * 8]);
        a = __builtin_amdgcn_mfma_f32_16x16x32_bf16(aH, bf[ks], a, 0, 0, 0);
      }
#pragma unroll
      for (int rg = 0; rg < 4; ++rg) {
        int r = m5 * 16 + quad * 4 + rg;
        int p = r / 20;
        atomicMax(&sAgg[p * 64 + c], fmap(a[rg]));
      }
    }
  }
  __syncthreads();

  {
    int p = t >> 6, cc = t & 63;
    agg[((size_t)(b * NN + i0 + p)) * CC + cc] = funmap(sAgg[t]);
  }
}

// ---------------------------------------------------------------- K3a: SE partial sums (256 blocks)
__global__ void k_se1(const float* __restrict__ agg, float* __restrict__ part) {
  int b = blockIdx.x >> 4, ch = blockIdx.x & 15;
  int t = threadIdx.x;
  int c = t & 63, q = t >> 6;
  __shared__ float red[4][64];
  const float* ab = agg + ((size_t)(b * NN) + ch * 128) * CC;
  float s = 0.f;
  for (int r = q * 32; r < q * 32 + 32; ++r) s += ab[(size_t)r * CC + c];
  red[q][c] = s;
  __syncthreads();
  if (t < 64)
    part[blockIdx.x * 64 + t] = (red[0][t] + red[1][t]) + (red[2][t] + red[3][t]);
}

// ---------------------------------------------------------------- K3b: SE finish (16 blocks x 64)
__global__ void k_se2(const float* __restrict__ part, const float* __restrict__ sew1,
                      const float* __restrict__ sew2, float* __restrict__ y) {
  int b = blockIdx.x, t = threadIdx.x;
  __shared__ float sv[64];
  __shared__ float hid[4];
  {
    float s = 0.f;
#pragma unroll
    for (int k = 0; k < 16; ++k) s += part[(b * 16 + k) * 64 + t];
    sv[t] = s * (1.f / 2048.f);
  }
  __syncthreads();
  if (t < 4) {
    float a = 0.f;
    for (int cc = 0; cc < 64; ++cc) a += sv[cc] * sew1[cc * 4 + t];
    hid[t] = fmaxf(a, 0.f);
  }
  __syncthreads();
  {
    float a = 0.f;
#pragma unroll
    for (int h = 0; h < 4; ++h) a += hid[h] * sew2[h * 64 + t];
    y[b * 64 + t] = 1.f / (1.f + expf(-a));
  }
}

// ---------------------------------------------------------------- K4: per-point stats (f32)
__global__ void k_stats(const float* __restrict__ agg, const float* __restrict__ y,
                        float* __restrict__ ycat) {
  int t = threadIdx.x;
  int gid = blockIdx.x * 4 + (t >> 6);
  int l = t & 63;
  int b = gid >> 11, i = gid & 2047;
  float v = agg[(size_t)gid * CC + l] * y[b * 64 + l];
  float s = v, mx = v;
#pragma unroll
  for (int off = 32; off > 0; off >>= 1) {
    s += __shfl_xor(s, off);
    mx = fmaxf(mx, __shfl_xor(mx, off));
  }
  if (l == 0) {
    ycat[b * 2 * NN + i] = s * (1.f / 64.f);
    ycat[b * 2 * NN + NN + i] = mx;
  }
}

// ---------------------------------------------------------------- K5: conv7 att + add (f32 out)
__global__ void k_final(const float* __restrict__ agg, const float* __restrict__ y,
                        const float* __restrict__ ycat, const float* __restrict__ saw,
                        const float* __restrict__ x, float* __restrict__ out) {
  int e = blockIdx.x * 256 + threadIdx.x;
  int ifl = e >> 6, c = e & 63;
  int b = ifl >> 11, i = ifl & 2047;
  float a = 0.f;
#pragma unroll
  for (int w = 0; w < 7; ++w) {
    int ii = i + w - 3;
    if (ii >= 0 && ii < NN) {
      a += ycat[b * 2 * NN + ii] * saw[w];
      a += ycat[b * 2 * NN + NN + ii] * saw[7 + w];
    }
  }
  float att = 1.f / (1.f + expf(-a));
  out[e] = agg[(size_t)ifl * CC + c] * y[b * 64 + c] * att + x[(size_t)e];
}

// ----------------------------------------------------------------
extern "C" void kernel_launch(void* const* d_in, const int* in_sizes, int n_in,
                              void* d_out, int out_size, void* d_ws, size_t ws_size,
                              hipStream_t stream) {
  const float* x    = (const float*)d_in[0];
  const float* w1   = (const float*)d_in[3];
  const float* b1   = (const float*)d_in[4];
  const float* w2   = (const float*)d_in[5];
  const float* b2   = (const float*)d_in[6];
  const float* w3   = (const float*)d_in[7];
  const float* b3   = (const float*)d_in[8];
  const float* sew1 = (const float*)d_in[9];
  const float* sew2 = (const float*)d_in[10];
  const float* saw  = (const float*)d_in[11];
  float* out = (float*)d_out;

  char* ws = (char*)d_ws;
  float*   sq   = (float*)  (ws);                          // 131072 B
  int*     idx  = (int*)    (ws + 131072);                 // 2621440 B
  float*   part = (float*)  (ws + 131072);                 // 65536 B (aliases idx; idx is
                                                           // consumed by k_mlp before k_se1)
  ushortT* cand = (ushortT*)(ws + 2752512);                // 5242880 B (32768*80 u16)
  float*   agg  = (float*)  (ws + 2752512);                // 8388608 B (aliases cand; cand
                                                           // consumed before k_mlp writes)
  float*   y    = (float*)  (ws + 11141120);               // 4096 B
  float*   ycat = (float*)  (ws + 11145216);               // 262144 B
  ushortT* wbf  = (ushortT*)(ws + 11407360);               // 32768 B -> total 11440128 B

  // bf16 image of x lives in d_out (4 MB of its 8 MB) until k_final overwrites it.
  ushortT* xbf = (ushortT*)d_out;

  k_wconv <<<1,              256, 0, stream>>>(w1, w2, w3, wbf);
  k_sq    <<<128,            256, 0, stream>>>(x, sq, xbf);
  k_knn   <<<dim3(64, 16),   256, 0, stream>>>(xbf, sq, cand);
  k_rerank<<<dim3(128, 16),  256, 0, stream>>>(x, cand, idx);
  k_mlp   <<<dim3(512, 16),  256, 0, stream>>>(x, xbf, idx, wbf, b1, b2, b3, agg);
  k_se1   <<<256,            256, 0, stream>>>(agg, part);
  k_se2   <<<16,             64,  0, stream>>>(part, sew1, sew2, y);
  k_stats <<<8192,           256, 0, stream>>>(agg, y, ycat);
  k_final <<<8192,           256, 0, stream>>>(agg, y, ycat, saw, x, out);
}

// Round 14
// 305.530 us; speedup vs baseline: 1.1849x; 1.0672x over previous
//
#include <hip/hip_runtime.h>

typedef unsigned int uint32;
typedef unsigned long long uint64;
typedef unsigned short ushortT;
typedef __attribute__((ext_vector_type(8))) short short8;
typedef __attribute__((ext_vector_type(4))) short short4v;
typedef __attribute__((ext_vector_type(4))) float floatx4;

#define DEV static __device__ __forceinline__

#define NN 2048
#define CC 64
#define KK 20

DEV float bf2f(ushortT h) {
  union { uint32 u; float f; } c; c.u = ((uint32)h) << 16; return c.f;
}
DEV ushortT f2bf(float f) {
  union { float f; uint32 u; } c; c.f = f;
  uint32 r = c.u + 0x7FFFu + ((c.u >> 16) & 1u);   // RNE
  return (ushortT)(r >> 16);
}
DEV void split2(float v, ushortT& h, ushortT& l) {
  h = f2bf(v);
  l = f2bf(v - bf2f(h));
}
DEV uint32 fmap(float f) {            // monotone f32 -> u32
  uint32 u = __float_as_uint(f);
  return (u & 0x80000000u) ? ~u : (u | 0x80000000u);
}
DEV float funmap(uint32 m) {
  uint32 u = (m & 0x80000000u) ? (m ^ 0x80000000u) : ~m;
  return __uint_as_float(u);
}
DEV short8 ld8(const ushortT* p) {    // 8B-aligned 16B load as two b64
  short4v a = *(const short4v*)p;
  short4v b = *(const short4v*)(p + 4);
  short8 r;
  r[0] = a.x; r[1] = a.y; r[2] = a.z; r[3] = a.w;
  r[4] = b.x; r[5] = b.y; r[6] = b.z; r[7] = b.w;
  return r;
}

// ---------------------------------------------------------------- K0: sq norms + bf16 image of x
__global__ void k_sq(const float* __restrict__ x, float* __restrict__ sq,
                     ushortT* __restrict__ xbf) {
  int p = blockIdx.x * 256 + threadIdx.x;
  const float4* row = (const float4*)(x + (size_t)p * CC);
  ushortT* orow = xbf + (size_t)p * CC;
  float s = 0.f;
#pragma unroll
  for (int q = 0; q < 16; ++q) {
    float4 v = row[q];
    s += v.x * v.x + v.y * v.y + v.z * v.z + v.w * v.w;
    short4v h;
    h.x = (short)f2bf(v.x); h.y = (short)f2bf(v.y);
    h.z = (short)f2bf(v.z); h.w = (short)f2bf(v.w);
    *(short4v*)(orow + q * 4) = h;
  }
  sq[p] = s;
}

// ---------------------------------------------------------------- K0b: one-time weight transpose+bf16
__global__ void k_wconv(const float* __restrict__ w1, const float* __restrict__ w2,
                        const float* __restrict__ w3, ushortT* __restrict__ wbf) {
  int t = threadIdx.x;
  for (int e = t; e < 4096; e += 256) {
    int n = e >> 6, k = e & 63;
    wbf[e]         = f2bf(w1[k * 64 + n]);
    wbf[4096 + e]  = f2bf(w1[(64 + k) * 64 + n]);
    wbf[8192 + e]  = f2bf(w2[k * 64 + n]);
    wbf[12288 + e] = f2bf(w3[k * 64 + n]);
  }
}

// ---------------------------------------------------------------- K1: KNN stage 1
// REVERTED to the round-11 form (78.5us, VGPR 64, no spill): 32-row i-tiles,
// 128-wide j-tiles, LDS 35.9KB, 4 blocks/CU. The 64-wide-tile experiment
// (rounds 12/13) is closed: under launch_bounds (256,8)->(256,6) the compiler
// under-allocates VGPRs (32/40) and spills the lst[20] ladder (22MB/6MB
// scratch writes, 137/97us). Ladder kernels need the full 128-VGPR budget.
__launch_bounds__(256, 4)
__global__ void k_knn(const ushortT* __restrict__ xbf, const float* __restrict__ sq,
                      ushortT* __restrict__ cand) {
  const int b  = blockIdx.y;
  const int i0 = blockIdx.x * 32;
  const int t  = threadIdx.x;
  const int l  = t & 63, wv = t >> 6;
  const int la = l & 15, quad = l >> 4;
  const int pp = t >> 2, ss = t & 3;     // owners: t<128 -> rows 0..31

  __shared__ __align__(16) char sm[35968];
  ushortT (*sXj)[72]    = (ushortT(*)[72])(sm);            // 18432 B
  uint32  (*sCand)[130] = (uint32(*)[130])(sm + 18432);    // 16640 B -> 35072
  uint32*  sTau         = (uint32*)(sm + 35072);           // 128 B -> 35200
  uint32*  sCnt         = (uint32*)(sm + 35200);           // 128 B -> 35328
  float*   sSqi         = (float*)(sm + 35328);            // 128 B -> 35456
  float*   sSqj         = (float*)(sm + 35456);            // 512 B -> 35968

  const ushortT* xbb = xbf + ((size_t)b * NN) * CC;

  const int mw  = wv & 1;            // which 16-row m-tile of the 32
  const int nt0 = (wv >> 1) * 4;     // 4 n-tiles of 16 j each

  short8 afrag[2];
  {
    const ushortT* rowp = xbb + (size_t)(i0 + mw * 16 + la) * CC;
#pragma unroll
    for (int ks = 0; ks < 2; ++ks)
      afrag[ks] = *(const short8*)(rowp + ks * 32 + quad * 8);
  }
  if (t < 32) sSqi[t] = sq[b * NN + i0 + t];

  {
    int r = t >> 1, co = (t & 1) * 32;
    const ushortT* src = xbb + (size_t)r * CC + co;
#pragma unroll
    for (int i = 0; i < 4; ++i)
      *(uint4*)&sXj[r][co + i * 8] = *(const uint4*)(src + i * 8);
  }
  if (t < 128) sSqj[t] = sq[b * NN + t];

  uint32 lst[KK];
#pragma unroll
  for (int s = 0; s < KK; ++s) lst[s] = 0xFFFFFFFFu;

  __syncthreads();

  float sqa[4];
  {
    float4 v = *(const float4*)&sSqi[mw * 16 + quad * 4];
    sqa[0] = v.x; sqa[1] = v.y; sqa[2] = v.z; sqa[3] = v.w;
  }

  for (int jt = 0; jt < 16; ++jt) {
    const int j0 = jt * 128;

    floatx4 acc[4];
#pragma unroll
    for (int n = 0; n < 4; ++n) acc[n] = (floatx4){0.f, 0.f, 0.f, 0.f};

#pragma unroll
    for (int ks = 0; ks < 2; ++ks) {
      int kof = ks * 32 + quad * 8;
#pragma unroll
      for (int n = 0; n < 4; ++n) {
        short8 bv = *(const short8*)&sXj[(nt0 + n) * 16 + la][kof];
        acc[n] = __builtin_amdgcn_mfma_f32_16x16x32_bf16(afrag[ks], bv, acc[n], 0, 0, 0);
      }
    }

    if (jt == 0) {
#pragma unroll
      for (int n = 0; n < 4; ++n) {
        int jl = (nt0 + n) * 16 + la;
        float dj = sSqj[jl];
        uint32 jg = (uint32)(j0 + jl);
#pragma unroll
        for (int rg = 0; rg < 4; ++rg) {
          int il = mw * 16 + quad * 4 + rg;
          float d = fmaxf(sqa[rg] + dj - 2.0f * acc[n][rg], 0.f);
          sCand[il][jl] = (__float_as_uint(d) & 0xFFFFF800u) | jg;
        }
      }
    } else {
      uint32 tv[4];
      {
        uint4 u = *(const uint4*)&sTau[mw * 16 + quad * 4];
        tv[0] = u.x; tv[1] = u.y; tv[2] = u.z; tv[3] = u.w;
      }
#pragma unroll
      for (int n = 0; n < 4; ++n) {
        int jl = (nt0 + n) * 16 + la;
        float dj = sSqj[jl];
        uint32 jg = (uint32)(j0 + jl);
#pragma unroll
        for (int rg = 0; rg < 4; ++rg) {
          int il = mw * 16 + quad * 4 + rg;
          float d = fmaxf(sqa[rg] + dj - 2.0f * acc[n][rg], 0.f);
          uint32 key = (__float_as_uint(d) & 0xFFFFF800u) | jg;
          if (key < tv[rg]) {
            uint32 slot = atomicAdd(&sCnt[il], 1u);
            sCand[il][slot] = key;
          }
        }
      }
    }
    __syncthreads();

    if (t < 128) {
      int cnt = (jt == 0) ? 128 : (int)sCnt[pp];
      for (int q = ss; q < cnt; q += 4) {
        uint32 cur = sCand[pp][q];
#pragma unroll
        for (int s = 0; s < KK; ++s) {
          uint32 lo = min(lst[s], cur);
          cur = max(lst[s], cur);
          lst[s] = lo;
        }
      }
      uint32 m19 = lst[KK - 1];
      m19 = min(m19, (uint32)__shfl_xor((int)m19, 1));
      m19 = min(m19, (uint32)__shfl_xor((int)m19, 2));
      if (ss == 0) { sTau[pp] = m19; sCnt[pp] = 0u; }
    }

    if (jt < 15) {
      const int jn = (jt + 1) * 128;
      int r = t >> 1, co = (t & 1) * 32;
      const ushortT* src = xbb + (size_t)(jn + r) * CC + co;
#pragma unroll
      for (int i = 0; i < 4; ++i)
        *(uint4*)&sXj[r][co + i * 8] = *(const uint4*)(src + i * 8);
      if (t < 128) sSqj[t] = sq[b * NN + jn + t];
    }
    __syncthreads();
  }

  if (t < 128) {
    size_t base = ((size_t)(b * NN + i0 + pp)) * 80 + ss * KK;
#pragma unroll
    for (int s = 0; s < KK; ++s) cand[base + s] = (ushortT)(lst[s] & 2047u);
  }
}

// ---------------------------------------------------------------- K1b: exact f64 rerank (round-11 passing form)
__launch_bounds__(256, 4)
__global__ void k_rerank(const float* __restrict__ x, const ushortT* __restrict__ cand,
                         int* __restrict__ idxout) {
  const int b  = blockIdx.y;
  const int i0 = blockIdx.x * 16;
  const int t  = threadIdx.x;
  const int grp = t >> 4, lg = t & 15;

  __shared__ double sK[16][81];

  const float* xb = x + ((size_t)b * NN) * CC;
  const int p = i0 + grp;
  float4 vi = ((const float4*)(xb + (size_t)p * CC))[lg];
  size_t cb = ((size_t)(b * NN + p)) * 80;

  const bool hi8 = (lg & 8) != 0;
  const bool hi4 = (lg & 4) != 0;
  const bool hi2 = (lg & 2) != 0;
  const int  uslot = ((lg >> 1) & 1) | (((lg >> 2) & 1) << 1) | (((lg >> 3) & 1) << 2);

  for (int q0 = 0; q0 < 80; q0 += 8) {
    int jj0 = (int)cand[cb + q0 + 0], jj1 = (int)cand[cb + q0 + 1];
    int jj2 = (int)cand[cb + q0 + 2], jj3 = (int)cand[cb + q0 + 3];
    int jj4 = (int)cand[cb + q0 + 4], jj5 = (int)cand[cb + q0 + 5];
    int jj6 = (int)cand[cb + q0 + 6], jj7 = (int)cand[cb + q0 + 7];

#define DISTQ(JJ, DD)                                                        \
    double DD;                                                               \
    {                                                                        \
      float4 vj = ((const float4*)(xb + (size_t)(JJ) * CC))[lg];             \
      double e0 = (double)vi.x - (double)vj.x;                               \
      double e1 = (double)vi.y - (double)vj.y;                               \
      double e2 = (double)vi.z - (double)vj.z;                               \
      double e3 = (double)vi.w - (double)vj.w;                               \
      DD = e0 * e0 + e1 * e1 + e2 * e2 + e3 * e3;                            \
    }
    DISTQ(jj0, dd0) DISTQ(jj1, dd1) DISTQ(jj2, dd2) DISTQ(jj3, dd3)
    DISTQ(jj4, dd4) DISTQ(jj5, dd5) DISTQ(jj6, dd6) DISTQ(jj7, dd7)
#undef DISTQ

    double m0 = hi8 ? dd4 : dd0, s0 = hi8 ? dd0 : dd4;
    double m1 = hi8 ? dd5 : dd1, s1 = hi8 ? dd1 : dd5;
    double m2 = hi8 ? dd6 : dd2, s2 = hi8 ? dd2 : dd6;
    double m3 = hi8 ? dd7 : dd3, s3 = hi8 ? dd3 : dd7;
    double r40 = m0 + __shfl_xor(s0, 8, 16);
    double r41 = m1 + __shfl_xor(s1, 8, 16);
    double r42 = m2 + __shfl_xor(s2, 8, 16);
    double r43 = m3 + __shfl_xor(s3, 8, 16);
    int j40 = hi8 ? jj4 : jj0, j41 = hi8 ? jj5 : jj1;
    int j42 = hi8 ? jj6 : jj2, j43 = hi8 ? jj7 : jj3;

    double n0 = hi4 ? r42 : r40, t0 = hi4 ? r40 : r42;
    double n1 = hi4 ? r43 : r41, t1 = hi4 ? r41 : r43;
    double r20 = n0 + __shfl_xor(t0, 4, 16);
    double r21 = n1 + __shfl_xor(t1, 4, 16);
    int j20 = hi4 ? j42 : j40, j21 = hi4 ? j43 : j41;

    double p0 = hi2 ? r21 : r20, u0 = hi2 ? r20 : r21;
    double r1 = p0 + __shfl_xor(u0, 2, 16);
    int j1 = hi2 ? j21 : j20;

    r1 += __shfl_xor(r1, 1, 16);

    if ((lg & 1) == 0) {
      uint64 bits = (uint64)__double_as_longlong(r1);   // d >= 0: order-preserving
      sK[grp][q0 + uslot] = __longlong_as_double((bits & ~2047ULL) | (uint64)j1);
    }
  }
  __syncthreads();

  double k5[5];
#pragma unroll
  for (int s = 0; s < 5; ++s) k5[s] = sK[grp][lg + 16 * s];

  const double DINF = __longlong_as_double(0x7FF0000000000000LL);
  size_t obase = ((size_t)(b * NN + p)) * KK;
  for (int r = 0; r < KK; ++r) {
    double lm = fmin(fmin(fmin(k5[0], k5[1]), fmin(k5[2], k5[3])), k5[4]);
#pragma unroll
    for (int off = 8; off > 0; off >>= 1)
      lm = fmin(lm, __shfl_xor(lm, off, 16));
#pragma unroll
    for (int s = 0; s < 5; ++s) k5[s] = (k5[s] == lm) ? DINF : k5[s];
    if (lg == (r & 15))
      idxout[obase + r] = (int)((uint64)__double_as_longlong(lm) & 2047ULL);
  }
}

// ---------------------------------------------------------------- K2: edge MLP + max-agg (unchanged)
__launch_bounds__(256, 4)
__global__ void k_mlp(const float* __restrict__ x, const ushortT* __restrict__ xbf,
                      const int* __restrict__ idx, const ushortT* __restrict__ wbf,
                      const float* __restrict__ b1, const float* __restrict__ b2,
                      const float* __restrict__ b3, float* __restrict__ agg) {
  const int b  = blockIdx.y;
  const int i0 = blockIdx.x * 4;
  const int t  = threadIdx.x;
  const int l  = t & 63, wv = t >> 6;
  const int la = l & 15, quad = l >> 4;

  __shared__ __align__(16) char sm[35008];
  ushortT (*sDH)[68]  = (ushortT(*)[68])(sm + 0);
  ushortT (*sDL)[68]  = (ushortT(*)[68])(sm + 10880);
  ushortT (*sH1)[68]  = (ushortT(*)[68])(sm + 21760);
  float   (*sPre)[64] = (float(*)[64])(sm + 32640);
  uint32*  sAgg       = (uint32*)(sm + 33664);
  int*     sJ         = (int*)(sm + 34688);
  ushortT (*sH2)[68]  = sDH;

  const int c = wv * 16 + la;
  const ushortT* w1aT = wbf;
  const ushortT* w1bT = wbf + 4096;
  const ushortT* w2T  = wbf + 8192;
  const ushortT* w3T  = wbf + 12288;

  if (t < 80) {
    int p = t / 20, kk = t - p * 20;
    int v = idx[((size_t)(b * NN + i0 + p)) * KK + kk];
    v = v < 0 ? 0 : (v > (NN - 1) ? (NN - 1) : v);
    sJ[t] = v;
  }
  sAgg[t] = 0u;

  float b2c = b2[c], b3c = b3[c];

  {
    float b1c = b1[c];
    floatx4 ap = (floatx4){b1c, b1c, b1c, b1c};
#pragma unroll
    for (int ks = 0; ks < 2; ++ks) {
      short8 av = *(const short8*)(xbf + (size_t)(b * NN + i0 + (la & 3)) * CC + ks * 32 + quad * 8);
      short8 bv = *(const short8*)(w1aT + c * 64 + ks * 32 + quad * 8);
      ap = __builtin_amdgcn_mfma_f32_16x16x32_bf16(av, bv, ap, 0, 0, 0);
    }
    if (quad == 0) {
#pragma unroll
      for (int rg = 0; rg < 4; ++rg) sPre[rg][c] = ap[rg];
    }
  }
  __syncthreads();

  const float* xb = x + ((size_t)b * NN) * CC;
  for (int e = t; e < 1280; e += 256) {
    int r = e >> 4, c4g = e & 15, c4 = c4g * 4;
    int p = r / 20;
    float4 vi = ((const float4*)(xb + (size_t)(i0 + p) * CC))[c4g];
    float4 vj = ((const float4*)(xb + (size_t)sJ[r] * CC))[c4g];
    short4v dh, dl;
    ushortT hh, ll;
    split2(vj.x - vi.x, hh, ll); dh.x = (short)hh; dl.x = (short)ll;
    split2(vj.y - vi.y, hh, ll); dh.y = (short)hh; dl.y = (short)ll;
    split2(vj.z - vi.z, hh, ll); dh.z = (short)hh; dl.z = (short)ll;
    split2(vj.w - vi.w, hh, ll); dh.w = (short)hh; dl.w = (short)ll;
    *(short4v*)&sDH[r][c4] = dh;
    *(short4v*)&sDL[r][c4] = dl;
  }
  __syncthreads();

  {
    short8 bB[2];
#pragma unroll
    for (int ks = 0; ks < 2; ++ks)
      bB[ks] = *(const short8*)(w1bT + c * 64 + ks * 32 + quad * 8);
#pragma unroll
    for (int m5 = 0; m5 < 5; ++m5) {
      floatx4 a;
#pragma unroll
      for (int rg = 0; rg < 4; ++rg) {
        int r = m5 * 16 + quad * 4 + rg;
        a[rg] = sPre[r / 20][c];
      }
#pragma unroll
      for (int ks = 0; ks < 2; ++ks) {
        int kof = ks * 32 + quad * 8;
        short8 aDH = ld8(&sDH[m5 * 16 + la][kof]);
        short8 aDL = ld8(&sDL[m5 * 16 + la][kof]);
        a = __builtin_amdgcn_mfma_f32_16x16x32_bf16(aDH, bB[ks], a, 0, 0, 0);
        a = __builtin_amdgcn_mfma_f32_16x16x32_bf16(aDL, bB[ks], a, 0, 0, 0);
      }
#pragma unroll
      for (int rg = 0; rg < 4; ++rg) {
        int r = m5 * 16 + quad * 4 + rg;
        sH1[r][c] = f2bf(fmaxf(a[rg], 0.f));
      }
    }
  }
  __syncthreads();

  {
    short8 bf[2];
#pragma unroll
    for (int ks = 0; ks < 2; ++ks)
      bf[ks] = *(const short8*)(w2T + c * 64 + ks * 32 + quad * 8);
#pragma unroll
    for (int m5 = 0; m5 < 5; ++m5) {
      floatx4 a = (floatx4){b2c, b2c, b2c, b2c};
#pragma unroll
      for (int ks = 0; ks < 2; ++ks) {
        short8 aH = ld8(&sH1[m5 * 16 + la][ks * 32 + quad * 8]);
        a = __builtin_amdgcn_mfma_f32_16x16x32_bf16(aH, bf[ks], a, 0, 0, 0);
      }
#pragma unroll
      for (int rg = 0; rg < 4; ++rg) {
        int r = m5 * 16 + quad * 4 + rg;
        sH2[r][c] = f2bf(fmaxf(a[rg], 0.f));
      }
    }
  }
  __syncthreads();

  {
    short8 bf[2];
#pragma unroll
    for (int ks = 0; ks < 2; ++ks)
      bf[ks] = *(const short8*)(w3T + c * 64 + ks * 32 + quad * 8);
#pragma unroll
    for (int m5 = 0; m5 < 5; ++m5) {
      floatx4 a = (floatx4){b3c, b3c, b3c, b3c};
#pragma unroll
      for (int ks = 0; ks < 2; ++ks) {
        short8 aH = ld8(&sH2[m5 * 16 + la][ks * 32 + quad * 8]);
        a = __builtin_amdgcn_mfma_f32_16x16x32_bf16(aH, bf[ks], a, 0, 0, 0);
      }
#pragma unroll
      for (int rg = 0; rg < 4; ++rg) {
        int r = m5 * 16 + quad * 4 + rg;
        int p = r / 20;
        atomicMax(&sAgg[p * 64 + c], fmap(a[rg]));
      }
    }
  }
  __syncthreads();

  {
    int p = t >> 6, cc = t & 63;
    agg[((size_t)(b * NN + i0 + p)) * CC + cc] = funmap(sAgg[t]);
  }
}

// ---------------------------------------------------------------- K3a: SE partial sums (256 blocks)
__global__ void k_se1(const float* __restrict__ agg, float* __restrict__ part) {
  int b = blockIdx.x >> 4, ch = blockIdx.x & 15;
  int t = threadIdx.x;
  int c = t & 63, q = t >> 6;
  __shared__ float red[4][64];
  const float* ab = agg + ((size_t)(b * NN) + ch * 128) * CC;
  float s = 0.f;
  for (int r = q * 32; r < q * 32 + 32; ++r) s += ab[(size_t)r * CC + c];
  red[q][c] = s;
  __syncthreads();
  if (t < 64)
    part[blockIdx.x * 64 + t] = (red[0][t] + red[1][t]) + (red[2][t] + red[3][t]);
}

// ---------------------------------------------------------------- K3b: SE finish (16 blocks x 64)
__global__ void k_se2(const float* __restrict__ part, const float* __restrict__ sew1,
                      const float* __restrict__ sew2, float* __restrict__ y) {
  int b = blockIdx.x, t = threadIdx.x;
  __shared__ float sv[64];
  __shared__ float hid[4];
  {
    float s = 0.f;
#pragma unroll
    for (int k = 0; k < 16; ++k) s += part[(b * 16 + k) * 64 + t];
    sv[t] = s * (1.f / 2048.f);
  }
  __syncthreads();
  if (t < 4) {
    float a = 0.f;
    for (int cc = 0; cc < 64; ++cc) a += sv[cc] * sew1[cc * 4 + t];
    hid[t] = fmaxf(a, 0.f);
  }
  __syncthreads();
  {
    float a = 0.f;
#pragma unroll
    for (int h = 0; h < 4; ++h) a += hid[h] * sew2[h * 64 + t];
    y[b * 64 + t] = 1.f / (1.f + expf(-a));
  }
}

// ---------------------------------------------------------------- K4: per-point stats (f32)
__global__ void k_stats(const float* __restrict__ agg, const float* __restrict__ y,
                        float* __restrict__ ycat) {
  int t = threadIdx.x;
  int gid = blockIdx.x * 4 + (t >> 6);
  int l = t & 63;
  int b = gid >> 11, i = gid & 2047;
  float v = agg[(size_t)gid * CC + l] * y[b * 64 + l];
  float s = v, mx = v;
#pragma unroll
  for (int off = 32; off > 0; off >>= 1) {
    s += __shfl_xor(s, off);
    mx = fmaxf(mx, __shfl_xor(mx, off));
  }
  if (l == 0) {
    ycat[b * 2 * NN + i] = s * (1.f / 64.f);
    ycat[b * 2 * NN + NN + i] = mx;
  }
}

// ---------------------------------------------------------------- K5: conv7 att + add (f32 out)
__global__ void k_final(const float* __restrict__ agg, const float* __restrict__ y,
                        const float* __restrict__ ycat, const float* __restrict__ saw,
                        const float* __restrict__ x, float* __restrict__ out) {
  int e = blockIdx.x * 256 + threadIdx.x;
  int ifl = e >> 6, c = e & 63;
  int b = ifl >> 11, i = ifl & 2047;
  float a = 0.f;
#pragma unroll
  for (int w = 0; w < 7; ++w) {
    int ii = i + w - 3;
    if (ii >= 0 && ii < NN) {
      a += ycat[b * 2 * NN + ii] * saw[w];
      a += ycat[b * 2 * NN + NN + ii] * saw[7 + w];
    }
  }
  float att = 1.f / (1.f + expf(-a));
  out[e] = agg[(size_t)ifl * CC + c] * y[b * 64 + c] * att + x[(size_t)e];
}

// ----------------------------------------------------------------
extern "C" void kernel_launch(void* const* d_in, const int* in_sizes, int n_in,
                              void* d_out, int out_size, void* d_ws, size_t ws_size,
                              hipStream_t stream) {
  const float* x    = (const float*)d_in[0];
  const float* w1   = (const float*)d_in[3];
  const float* b1   = (const float*)d_in[4];
  const float* w2   = (const float*)d_in[5];
  const float* b2   = (const float*)d_in[6];
  const float* w3   = (const float*)d_in[7];
  const float* b3   = (const float*)d_in[8];
  const float* sew1 = (const float*)d_in[9];
  const float* sew2 = (const float*)d_in[10];
  const float* saw  = (const float*)d_in[11];
  float* out = (float*)d_out;

  char* ws = (char*)d_ws;
  float*   sq   = (float*)  (ws);                          // 131072 B
  int*     idx  = (int*)    (ws + 131072);                 // 2621440 B
  float*   part = (float*)  (ws + 131072);                 // 65536 B (aliases idx; idx is
                                                           // consumed by k_mlp before k_se1)
  ushortT* cand = (ushortT*)(ws + 2752512);                // 5242880 B (32768*80 u16)
  float*   agg  = (float*)  (ws + 2752512);                // 8388608 B (aliases cand; cand
                                                           // consumed before k_mlp writes)
  float*   y    = (float*)  (ws + 11141120);               // 4096 B
  float*   ycat = (float*)  (ws + 11145216);               // 262144 B
  ushortT* wbf  = (ushortT*)(ws + 11407360);               // 32768 B -> total 11440128 B

  // bf16 image of x lives in d_out (4 MB of its 8 MB) until k_final overwrites it.
  ushortT* xbf = (ushortT*)d_out;

  k_wconv <<<1,              256, 0, stream>>>(w1, w2, w3, wbf);
  k_sq    <<<128,            256, 0, stream>>>(x, sq, xbf);
  k_knn   <<<dim3(64, 16),   256, 0, stream>>>(xbf, sq, cand);
  k_rerank<<<dim3(128, 16),  256, 0, stream>>>(x, cand, idx);
  k_mlp   <<<dim3(512, 16),  256, 0, stream>>>(x, xbf, idx, wbf, b1, b2, b3, agg);
  k_se1   <<<256,            256, 0, stream>>>(agg, part);
  k_se2   <<<16,             64,  0, stream>>>(part, sew1, sew2, y);
  k_stats <<<8192,           256, 0, stream>>>(agg, y, ycat);
  k_final <<<8192,           256, 0, stream>>>(agg, y, ycat, saw, x, out);
}